// Round 13
// baseline (229.444 us; speedup 1.0000x reference)
//
#include <hip/hip_runtime.h>
#include <hip/hip_bf16.h>
#include <math.h>

// Problem constants
#define B_SZ 8
#define N_SZ 1024
#define D_IN 3072
#define H_SZ 128
#define NH 4
#define DH 32
#define TWO_H 256
#define LN_EPS 1e-5f
#define CAP 1024   // max neighbors stored per row
#define PR 16      // rows per block: projection
#define FR 16      // rows per block: fusion
#define NH_STRIDE (N_SZ * H_SZ)

// ---------------------------------------------------------------------------
// 0) Transpose all GEMM weights once: WT[k][j] = W[j][k]. Coalesced writes.
//    wt layout (floats): [0] WTfu1(256x128) [32768] WTfu2 [65536] WTsk1(128x128)
//    [81920] WTsk2 [98304] WTf1 [114688] WTr1 [131072] WTf2 [147456] WTr2
// ---------------------------------------------------------------------------
__global__ void transw_kernel(const float* __restrict__ Wfu1, const float* __restrict__ Wfu2,
                              const float* __restrict__ Wsk1, const float* __restrict__ Wsk2,
                              const float* __restrict__ Wf1, const float* __restrict__ Wr1,
                              const float* __restrict__ Wf2, const float* __restrict__ Wr2,
                              float* __restrict__ wt) {
    const int m = blockIdx.y;
    const int k = blockIdx.x;      // 0..255
    const int j = threadIdx.x;     // 0..127
    const float* W; float* out; int K;
    switch (m) {
      case 0: W = Wfu1; out = wt;           K = 256; break;
      case 1: W = Wfu2; out = wt + 32768;   K = 256; break;
      case 2: W = Wsk1; out = wt + 65536;   K = 128; break;
      case 3: W = Wsk2; out = wt + 81920;   K = 128; break;
      case 4: W = Wf1;  out = wt + 98304;   K = 128; break;
      case 5: W = Wr1;  out = wt + 114688;  K = 128; break;
      case 6: W = Wf2;  out = wt + 131072;  K = 128; break;
      default: W = Wr2; out = wt + 147456;  K = 128; break;
    }
    if (k >= K) return;
    out[k * H_SZ + j] = W[(size_t)j * K + k];
}

// ---------------------------------------------------------------------------
// 1a) enc1: z[b][j] = b1[j] + dot(stim[b,:], W1[j,:])
// ---------------------------------------------------------------------------
__global__ void enc1_kernel(const float* __restrict__ stim,
                            const float* __restrict__ W1, const float* __restrict__ b1,
                            float* __restrict__ z) {
    const int j = blockIdx.x;     // 0..255
    const int tid = threadIdx.x;  // 0..255
    const float4* w4 = (const float4*)(W1 + (size_t)j * D_IN);
    const float4* s4 = (const float4*)stim;

    float acc[B_SZ];
    #pragma unroll
    for (int b = 0; b < B_SZ; ++b) acc[b] = 0.0f;

    #pragma unroll
    for (int i = 0; i < D_IN / 4 / 256; ++i) {  // 3 iters
        const int k4 = tid + i * 256;
        const float4 w = w4[k4];
        #pragma unroll
        for (int b = 0; b < B_SZ; ++b) {
            const float4 s = s4[b * (D_IN / 4) + k4];
            acc[b] += s.x * w.x + s.y * w.y + s.z * w.z + s.w * w.w;
        }
    }

    #pragma unroll
    for (int b = 0; b < B_SZ; ++b) {
        float v = acc[b];
        v += __shfl_xor(v, 1);  v += __shfl_xor(v, 2);  v += __shfl_xor(v, 4);
        v += __shfl_xor(v, 8);  v += __shfl_xor(v, 16); v += __shfl_xor(v, 32);
        acc[b] = v;
    }
    __shared__ float red[4][B_SZ];
    const int wave = tid >> 6, lane = tid & 63;
    if (lane == 0) {
        #pragma unroll
        for (int b = 0; b < B_SZ; ++b) red[wave][b] = acc[b];
    }
    __syncthreads();
    if (tid < B_SZ) {
        float v = red[0][tid] + red[1][tid] + red[2][tid] + red[3][tid];
        z[tid * TWO_H + j] = v + b1[j];
    }
}

// ---------------------------------------------------------------------------
// 1b) enc2: LayerNorm + exact GELU over z rows. grid = 8 blocks x 256 threads.
// ---------------------------------------------------------------------------
__global__ void enc2_kernel(const float* __restrict__ z,
                            const float* __restrict__ lng, const float* __restrict__ lnb,
                            float* __restrict__ zg) {
    __shared__ float red[TWO_H];
    const int b = blockIdx.x;
    const int tid = threadIdx.x;

    float zi = z[b * TWO_H + tid];
    red[tid] = zi; __syncthreads();
    for (int s = 128; s > 0; s >>= 1) { if (tid < s) red[tid] += red[tid + s]; __syncthreads(); }
    float mu = red[0] * (1.0f / TWO_H);
    __syncthreads();
    float dz = zi - mu;
    red[tid] = dz * dz; __syncthreads();
    for (int s = 128; s > 0; s >>= 1) { if (tid < s) red[tid] += red[tid + s]; __syncthreads(); }
    float var = red[0] * (1.0f / TWO_H);

    float zn = dz * (1.0f / sqrtf(var + LN_EPS)) * lng[tid] + lnb[tid];
    zg[b * TWO_H + tid] = 0.5f * zn * (1.0f + erff(zn * 0.70710678118654752f));
}

// ---------------------------------------------------------------------------
// 1c) enc3: g[b][j] = b2[j] + dot(zg[b,:], W2[j,:])
// ---------------------------------------------------------------------------
__global__ void enc3_kernel(const float* __restrict__ zg,
                            const float* __restrict__ W2, const float* __restrict__ b2,
                            float* __restrict__ g) {
    const int j = blockIdx.x;     // 0..127
    const int tid = threadIdx.x;  // 0..255
    const float w = W2[(size_t)j * TWO_H + tid];

    float acc[B_SZ];
    #pragma unroll
    for (int b = 0; b < B_SZ; ++b) acc[b] = zg[b * TWO_H + tid] * w;

    #pragma unroll
    for (int b = 0; b < B_SZ; ++b) {
        float v = acc[b];
        v += __shfl_xor(v, 1);  v += __shfl_xor(v, 2);  v += __shfl_xor(v, 4);
        v += __shfl_xor(v, 8);  v += __shfl_xor(v, 16); v += __shfl_xor(v, 32);
        acc[b] = v;
    }
    __shared__ float red[4][B_SZ];
    const int wave = tid >> 6, lane = tid & 63;
    if (lane == 0) {
        #pragma unroll
        for (int b = 0; b < B_SZ; ++b) red[wave][b] = acc[b];
    }
    __syncthreads();
    if (tid < B_SZ)
        g[tid * H_SZ + j] = red[0][tid] + red[1][tid] + red[2][tid] + red[3][tid] + b2[j];
}

// ---------------------------------------------------------------------------
// 2) Build both neighbor lists. One WAVE per row; ballot-compaction preserves
//    ascending order. grid = (N_SZ, 2) x 64 threads.
// ---------------------------------------------------------------------------
__global__ void csr_kernel(const float* __restrict__ m0, const float* __restrict__ m1,
                           int* __restrict__ i0, int* __restrict__ i1,
                           int* __restrict__ d0, int* __restrict__ d1) {
    const float* mask = blockIdx.y ? m1 : m0;
    int* idx = blockIdx.y ? i1 : i0;
    int* deg = blockIdx.y ? d1 : d0;

    const int row = blockIdx.x;
    const int lane = threadIdx.x;  // 0..63
    const float* mrow = mask + (size_t)row * N_SZ;
    int* irow = idx + (size_t)row * CAP;

    int base = 0;
    #pragma unroll 4
    for (int t = 0; t < N_SZ / 64; ++t) {
        int c = t * 64 + lane;
        bool edge = (mrow[c] == 0.0f);
        unsigned long long ball = __ballot(edge);
        unsigned long long below = ball & ((1ull << lane) - 1ull);
        if (edge) irow[base + __popcll(below)] = c;
        base += __popcll(ball);
    }
    if (lane == 0) deg[row] = base;
}

// ---------------------------------------------------------------------------
// 3) x[b,n,c] = g[b,c] + voxel_emb[n,c]
// ---------------------------------------------------------------------------
__global__ void addemb_kernel(const float* __restrict__ g, const float* __restrict__ emb,
                              float* __restrict__ x) {
    int idx = blockIdx.x * blockDim.x + threadIdx.x;
    int c = idx & 127;
    int n = (idx >> 7) & 1023;
    int b = idx >> 17;
    x[idx] = g[b * H_SZ + c] + emb[n * H_SZ + c];
}

// ---------------------------------------------------------------------------
// 4) Projection with TRANSPOSED weights (coalesced weight loads).
//    grid = (BN/PR, 2) x 512 threads. thread = (jq = (tid&31)*4, r = tid>>5).
//    Per k: 1 coalesced float4 weight + 1 LDS broadcast + 4 FMA.
// ---------------------------------------------------------------------------
__global__ __launch_bounds__(512) void proj_kernel(
        const float* __restrict__ x, const float* __restrict__ wta,
        const float* __restrict__ wtb,
        float* __restrict__ outa, float* __restrict__ outb) {
    const float* WT = blockIdx.y ? wtb : wta;
    float* out = blockIdx.y ? outb : outa;

    __shared__ float xs[PR][H_SZ];
    const int row0 = blockIdx.x * PR;
    const int tid = threadIdx.x;     // 0..511
    const int jq = (tid & 31) * 4;   // channel quad base
    const int r  = tid >> 5;         // row 0..15

    for (int kk = tid; kk < PR * H_SZ / 4; kk += 512) {
        const int rr = kk >> 5, c4i = kk & 31;
        ((float4*)xs[rr])[c4i] = ((const float4*)(x + (size_t)(row0 + rr) * H_SZ))[c4i];
    }
    __syncthreads();

    float a0 = 0.0f, a1 = 0.0f, a2 = 0.0f, a3 = 0.0f;
    #pragma unroll 8
    for (int k = 0; k < H_SZ; ++k) {
        const float4 w = *(const float4*)(WT + k * H_SZ + jq);
        const float xv = xs[r][k];
        a0 += xv * w.x; a1 += xv * w.y; a2 += xv * w.z; a3 += xv * w.w;
    }
    float4 v = {a0, a1, a2, a3};
    *(float4*)(out + (size_t)(row0 + r) * H_SZ + jq) = v;
}

// ---------------------------------------------------------------------------
// 5) Sparse masked attention + ELU, coalesced neighbor-parallel.
//    (round-10 proven config, unchanged)
// ---------------------------------------------------------------------------
__global__ __launch_bounds__(256) void attn_kernel(
        const float* __restrict__ Wha, const float* __restrict__ Whb,
        const int* __restrict__ ia, const int* __restrict__ ib,
        const int* __restrict__ da, const int* __restrict__ db,
        float* __restrict__ oa, float* __restrict__ ob) {
    const float* Wh = blockIdx.y ? Whb : Wha;
    const int* idx = blockIdx.y ? ib : ia;
    const int* deg = blockIdx.y ? db : da;
    float* out = blockIdx.y ? ob : oa;

    const int bid = blockIdx.x;
    const int b = bid & 7;                                  // batch -> XCD
    const int i = ((bid >> 3) << 2) | (threadIdx.x >> 6);   // row
    const int bi = b * N_SZ + i;
    const int lane = threadIdx.x & 63;
    const int c = lane & 31;      // 16B chunk id within a 512B row
    const int e2 = lane >> 5;     // which of the 2 edges per instruction

    // q chunk (4 floats of head c>>3), pre-scaled: 1/sqrt(32) * log2(e)
    float4 q4 = *(const float4*)(Wh + (size_t)bi * H_SZ + c * 4);
    q4.x *= 0.25505654741110714f; q4.y *= 0.25505654741110714f;
    q4.z *= 0.25505654741110714f; q4.w *= 0.25505654741110714f;

    const int dg = deg[i];
    const int* row = idx + (size_t)i * CAP;
    int idxv0 = row[lane] & 1023;
    int idxv1 = (dg > 64) ? (row[64 + lane] & 1023) : 0;

    const float* kbase = Wh + (size_t)b * NH_STRIDE;

    float4 acc = {0.0f, 0.0f, 0.0f, 0.0f};
    float l = 0.0f;

    const int nseg = (dg + 15) >> 4;
    for (int seg = 0; seg < nseg; ++seg) {
        const int srcv = (seg >= 4) ? idxv1 : idxv0;
        const int off16 = (seg & 3) << 4;
        float4 kv[8];
        #pragma unroll
        for (int t = 0; t < 8; ++t) {
            const int ja = __builtin_amdgcn_readlane(srcv, off16 + 2 * t);
            const int jb = __builtin_amdgcn_readlane(srcv, off16 + 2 * t + 1);
            const int j = e2 ? jb : ja;
            kv[t] = *(const float4*)(kbase + (size_t)j * H_SZ + c * 4);
        }
        const int ebase = seg << 4;
        #pragma unroll
        for (int t = 0; t < 8; ++t) {
            float s = q4.x * kv[t].x + q4.y * kv[t].y + q4.z * kv[t].z + q4.w * kv[t].w;
            s += __shfl_xor(s, 1);
            s += __shfl_xor(s, 2);
            s += __shfl_xor(s, 4);
            const bool valid = (ebase + 2 * t + e2) < dg;
            const float p = valid ? __builtin_amdgcn_exp2f(s) : 0.0f;
            l += p;
            acc.x += p * kv[t].x; acc.y += p * kv[t].y;
            acc.z += p * kv[t].z; acc.w += p * kv[t].w;
        }
    }

    l += __shfl_xor(l, 32);
    acc.x += __shfl_xor(acc.x, 32);
    acc.y += __shfl_xor(acc.y, 32);
    acc.z += __shfl_xor(acc.z, 32);
    acc.w += __shfl_xor(acc.w, 32);

    if (e2 == 0) {
        const float inv = 1.0f / l;
        float4 v;
        float hp;
        hp = acc.x * inv;
        v.x = (hp > 0.0f) ? hp : (__builtin_amdgcn_exp2f(hp * 1.4426950408889634f) - 1.0f);
        hp = acc.y * inv;
        v.y = (hp > 0.0f) ? hp : (__builtin_amdgcn_exp2f(hp * 1.4426950408889634f) - 1.0f);
        hp = acc.z * inv;
        v.z = (hp > 0.0f) ? hp : (__builtin_amdgcn_exp2f(hp * 1.4426950408889634f) - 1.0f);
        hp = acc.w * inv;
        v.w = (hp > 0.0f) ? hp : (__builtin_amdgcn_exp2f(hp * 1.4426950408889634f) - 1.0f);
        *(float4*)(out + (size_t)bi * H_SZ + c * 4) = v;
    }
}

// ---------------------------------------------------------------------------
// 6) Fusion with TRANSPOSED weights (+ optional fused readout).
//    grid = BN/FR = 512 blocks x 512 threads.
//    thread = (jq = (tid&31)*4, r = tid>>5): 4 channels x 1 row.
//    Per k: 1 coalesced float4 weight + 1 LDS broadcast + 4 FMA.
// ---------------------------------------------------------------------------
__global__ __launch_bounds__(512) void fusion_kernel(
        const float* __restrict__ hf, const float* __restrict__ hr,
        const float* __restrict__ x,
        const float* __restrict__ wtfu, const float* __restrict__ bfu,
        const float* __restrict__ wtsk, const float* __restrict__ bsk,
        float* __restrict__ out,
        const float* __restrict__ Wro, const float* __restrict__ bro,
        float* __restrict__ pred) {
    __shared__ float hfs[FR][H_SZ];
    __shared__ float hrs[FR][H_SZ];
    __shared__ float xs[FR][H_SZ];
    __shared__ float red[FR];
    const int row0 = blockIdx.x * FR;
    const int tid = threadIdx.x;     // 0..511
    const int jq = (tid & 31) * 4;   // channel quad base
    const int r  = tid >> 5;         // row 0..15

    for (int kk = tid; kk < FR * H_SZ / 4; kk += 512) {
        const int rr = kk >> 5, c4i = kk & 31;
        ((float4*)hfs[rr])[c4i] = ((const float4*)(hf + (size_t)(row0 + rr) * H_SZ))[c4i];
        ((float4*)hrs[rr])[c4i] = ((const float4*)(hr + (size_t)(row0 + rr) * H_SZ))[c4i];
        ((float4*)xs[rr])[c4i]  = ((const float4*)(x  + (size_t)(row0 + rr) * H_SZ))[c4i];
    }
    __syncthreads();

    float a0 = 0.0f, a1 = 0.0f, a2 = 0.0f, a3 = 0.0f;
    #pragma unroll 8
    for (int k = 0; k < H_SZ; ++k) {          // hf . Wfu[:,0:128]
        const float4 w = *(const float4*)(wtfu + k * H_SZ + jq);
        const float v = hfs[r][k];
        a0 += v * w.x; a1 += v * w.y; a2 += v * w.z; a3 += v * w.w;
    }
    #pragma unroll 8
    for (int k = 0; k < H_SZ; ++k) {          // hr . Wfu[:,128:256]
        const float4 w = *(const float4*)(wtfu + (H_SZ + k) * H_SZ + jq);
        const float v = hrs[r][k];
        a0 += v * w.x; a1 += v * w.y; a2 += v * w.z; a3 += v * w.w;
    }
    #pragma unroll 8
    for (int k = 0; k < H_SZ; ++k) {          // x . Wsk
        const float4 w = *(const float4*)(wtsk + k * H_SZ + jq);
        const float v = xs[r][k];
        a0 += v * w.x; a1 += v * w.y; a2 += v * w.z; a3 += v * w.w;
    }

    const float4 bf = *(const float4*)(bfu + jq);
    const float4 bs = *(const float4*)(bsk + jq);
    a0 += bf.x + bs.x; a1 += bf.y + bs.y; a2 += bf.z + bs.z; a3 += bf.w + bs.w;

    if (pred == nullptr) {
        float4 v = {a0, a1, a2, a3};
        *(float4*)(out + (size_t)(row0 + r) * H_SZ + jq) = v;
    } else {
        const float4 wr = *(const float4*)(Wro + jq);
        float t = a0 * wr.x + a1 * wr.y + a2 * wr.z + a3 * wr.w;
        t += __shfl_xor(t, 1);  t += __shfl_xor(t, 2);  t += __shfl_xor(t, 4);
        t += __shfl_xor(t, 8);  t += __shfl_xor(t, 16);
        if ((tid & 31) == 0) red[r] = t;   // one writer per row
        __syncthreads();
        if (tid < FR) pred[row0 + tid] = red[tid] + bro[0];
    }
}

// ---------------------------------------------------------------------------
extern "C" void kernel_launch(void* const* d_in, const int* in_sizes, int n_in,
                              void* d_out, int out_size, void* d_ws, size_t ws_size,
                              hipStream_t stream) {
    const float* stim   = (const float*)d_in[0];
    const float* W_enc1 = (const float*)d_in[1];
    const float* b_enc1 = (const float*)d_in[2];
    const float* ln_g   = (const float*)d_in[3];
    const float* ln_b   = (const float*)d_in[4];
    const float* W_enc2 = (const float*)d_in[5];
    const float* b_enc2 = (const float*)d_in[6];
    const float* vox    = (const float*)d_in[7];
    const float* W_f1   = (const float*)d_in[8];
    const float* W_r1   = (const float*)d_in[9];
    const float* W_f2   = (const float*)d_in[10];
    const float* W_r2   = (const float*)d_in[11];
    const float* W_fu1  = (const float*)d_in[12];
    const float* b_fu1  = (const float*)d_in[13];
    const float* W_fu2  = (const float*)d_in[14];
    const float* b_fu2  = (const float*)d_in[15];
    const float* W_sk1  = (const float*)d_in[16];
    const float* b_sk1  = (const float*)d_in[17];
    const float* W_sk2  = (const float*)d_in[18];
    const float* b_sk2  = (const float*)d_in[19];
    const float* W_ro   = (const float*)d_in[20];
    const float* b_ro   = (const float*)d_in[21];
    const float* mask_f = (const float*)d_in[22];
    const float* mask_r = (const float*)d_in[23];

    float* pred = (float*)d_out;

    // workspace layout (floats)
    float* ws  = (float*)d_ws;
    float* z   = ws;                    // 8*256
    float* zg  = z + 2048;              // 8*256
    float* g   = zg + 2048;             // 8*128
    float* x   = g + 1024;              // 8*1024*128
    float* Whf = x + 1048576;
    float* Whr = Whf + 1048576;
    float* hf  = Whr + 1048576;
    float* hr  = hf + 1048576;
    int* idxf  = (int*)(hr + 1048576);  // 1024*CAP
    int* idxr  = idxf + (size_t)N_SZ * CAP;
    int* degf  = idxr + (size_t)N_SZ * CAP;
    int* degr  = degf + N_SZ;
    float* wt  = (float*)(degr + N_SZ); // 163840 floats: transposed weights
    float* wtfu1 = wt;
    float* wtfu2 = wt + 32768;
    float* wtsk1 = wt + 65536;
    float* wtsk2 = wt + 81920;
    float* wtf1  = wt + 98304;
    float* wtr1  = wt + 114688;
    float* wtf2  = wt + 131072;
    float* wtr2  = wt + 147456;

    const int BN = B_SZ * N_SZ;  // 8192

    // weight transposes (independent of everything else)
    transw_kernel<<<dim3(256, 8), 128, 0, stream>>>(W_fu1, W_fu2, W_sk1, W_sk2,
                                                    W_f1, W_r1, W_f2, W_r2, wt);
    // encoder
    enc1_kernel<<<TWO_H, 256, 0, stream>>>(stim, W_enc1, b_enc1, z);
    enc2_kernel<<<B_SZ, 256, 0, stream>>>(z, ln_g, ln_b, zg);
    enc3_kernel<<<H_SZ, 256, 0, stream>>>(zg, W_enc2, b_enc2, g);
    // neighbor lists (both masks in one launch)
    csr_kernel<<<dim3(N_SZ, 2), 64, 0, stream>>>(mask_f, mask_r, idxf, idxr, degf, degr);
    // x = g + voxel_emb
    addemb_kernel<<<(BN * H_SZ) / 256, 256, 0, stream>>>(g, vox, x);

    // ---- GAT layer 1 ----
    proj_kernel<<<dim3(BN / PR, 2), 512, 0, stream>>>(x, wtf1, wtr1, Whf, Whr);
    attn_kernel<<<dim3(BN / 4, 2), 256, 0, stream>>>(Whf, Whr, idxf, idxr, degf, degr, hf, hr);
    fusion_kernel<<<BN / FR, 512, 0, stream>>>(hf, hr, x, wtfu1, b_fu1, wtsk1, b_sk1, x,
                                               nullptr, nullptr, nullptr);

    // ---- GAT layer 2 ----
    proj_kernel<<<dim3(BN / PR, 2), 512, 0, stream>>>(x, wtf2, wtr2, Whf, Whr);
    attn_kernel<<<dim3(BN / 4, 2), 256, 0, stream>>>(Whf, Whr, idxf, idxr, degf, degr, hf, hr);
    fusion_kernel<<<BN / FR, 512, 0, stream>>>(hf, hr, x, wtfu2, b_fu2, wtsk2, b_sk2, nullptr,
                                               W_ro, b_ro, pred);
}

// Round 14
// 222.291 us; speedup vs baseline: 1.0322x; 1.0322x over previous
//
#include <hip/hip_runtime.h>
#include <hip/hip_bf16.h>
#include <math.h>

// Problem constants
#define B_SZ 8
#define N_SZ 1024
#define D_IN 3072
#define H_SZ 128
#define NH 4
#define DH 32
#define TWO_H 256
#define LN_EPS 1e-5f
#define CAP 1024   // max neighbors stored per row
#define GR 16      // rows per block in GEMM kernels (proj/fusion)
#define NH_STRIDE (N_SZ * H_SZ)

// ---------------------------------------------------------------------------
// 0) Transpose all GEMM weights once: WT[k][j] = W[j][k]. Coalesced writes.
//    wt layout (floats): [0] WTfu1(256x128) [32768] WTfu2 [65536] WTsk1(128x128)
//    [81920] WTsk2 [98304] WTf1 [114688] WTr1 [131072] WTf2 [147456] WTr2
// ---------------------------------------------------------------------------
__global__ void transw_kernel(const float* __restrict__ Wfu1, const float* __restrict__ Wfu2,
                              const float* __restrict__ Wsk1, const float* __restrict__ Wsk2,
                              const float* __restrict__ Wf1, const float* __restrict__ Wr1,
                              const float* __restrict__ Wf2, const float* __restrict__ Wr2,
                              float* __restrict__ wt) {
    const int m = blockIdx.y;
    const int k = blockIdx.x;      // 0..255
    const int j = threadIdx.x;     // 0..127
    const float* W; float* out; int K;
    switch (m) {
      case 0: W = Wfu1; out = wt;           K = 256; break;
      case 1: W = Wfu2; out = wt + 32768;   K = 256; break;
      case 2: W = Wsk1; out = wt + 65536;   K = 128; break;
      case 3: W = Wsk2; out = wt + 81920;   K = 128; break;
      case 4: W = Wf1;  out = wt + 98304;   K = 128; break;
      case 5: W = Wr1;  out = wt + 114688;  K = 128; break;
      case 6: W = Wf2;  out = wt + 131072;  K = 128; break;
      default: W = Wr2; out = wt + 147456;  K = 128; break;
    }
    if (k >= K) return;
    out[k * H_SZ + j] = W[(size_t)j * K + k];
}

// ---------------------------------------------------------------------------
// 1a) enc1: z[b][j] = b1[j] + dot(stim[b,:], W1[j,:])
// ---------------------------------------------------------------------------
__global__ void enc1_kernel(const float* __restrict__ stim,
                            const float* __restrict__ W1, const float* __restrict__ b1,
                            float* __restrict__ z) {
    const int j = blockIdx.x;     // 0..255
    const int tid = threadIdx.x;  // 0..255
    const float4* w4 = (const float4*)(W1 + (size_t)j * D_IN);
    const float4* s4 = (const float4*)stim;

    float acc[B_SZ];
    #pragma unroll
    for (int b = 0; b < B_SZ; ++b) acc[b] = 0.0f;

    #pragma unroll
    for (int i = 0; i < D_IN / 4 / 256; ++i) {  // 3 iters
        const int k4 = tid + i * 256;
        const float4 w = w4[k4];
        #pragma unroll
        for (int b = 0; b < B_SZ; ++b) {
            const float4 s = s4[b * (D_IN / 4) + k4];
            acc[b] += s.x * w.x + s.y * w.y + s.z * w.z + s.w * w.w;
        }
    }

    #pragma unroll
    for (int b = 0; b < B_SZ; ++b) {
        float v = acc[b];
        v += __shfl_xor(v, 1);  v += __shfl_xor(v, 2);  v += __shfl_xor(v, 4);
        v += __shfl_xor(v, 8);  v += __shfl_xor(v, 16); v += __shfl_xor(v, 32);
        acc[b] = v;
    }
    __shared__ float red[4][B_SZ];
    const int wave = tid >> 6, lane = tid & 63;
    if (lane == 0) {
        #pragma unroll
        for (int b = 0; b < B_SZ; ++b) red[wave][b] = acc[b];
    }
    __syncthreads();
    if (tid < B_SZ) {
        float v = red[0][tid] + red[1][tid] + red[2][tid] + red[3][tid];
        z[tid * TWO_H + j] = v + b1[j];
    }
}

// ---------------------------------------------------------------------------
// 1b) enc2: LayerNorm + exact GELU over z rows. grid = 8 blocks x 256 threads.
// ---------------------------------------------------------------------------
__global__ void enc2_kernel(const float* __restrict__ z,
                            const float* __restrict__ lng, const float* __restrict__ lnb,
                            float* __restrict__ zg) {
    __shared__ float red[TWO_H];
    const int b = blockIdx.x;
    const int tid = threadIdx.x;

    float zi = z[b * TWO_H + tid];
    red[tid] = zi; __syncthreads();
    for (int s = 128; s > 0; s >>= 1) { if (tid < s) red[tid] += red[tid + s]; __syncthreads(); }
    float mu = red[0] * (1.0f / TWO_H);
    __syncthreads();
    float dz = zi - mu;
    red[tid] = dz * dz; __syncthreads();
    for (int s = 128; s > 0; s >>= 1) { if (tid < s) red[tid] += red[tid + s]; __syncthreads(); }
    float var = red[0] * (1.0f / TWO_H);

    float zn = dz * (1.0f / sqrtf(var + LN_EPS)) * lng[tid] + lnb[tid];
    zg[b * TWO_H + tid] = 0.5f * zn * (1.0f + erff(zn * 0.70710678118654752f));
}

// ---------------------------------------------------------------------------
// 1c) enc3: g[b][j] = b2[j] + dot(zg[b,:], W2[j,:])
// ---------------------------------------------------------------------------
__global__ void enc3_kernel(const float* __restrict__ zg,
                            const float* __restrict__ W2, const float* __restrict__ b2,
                            float* __restrict__ g) {
    const int j = blockIdx.x;     // 0..127
    const int tid = threadIdx.x;  // 0..255
    const float w = W2[(size_t)j * TWO_H + tid];

    float acc[B_SZ];
    #pragma unroll
    for (int b = 0; b < B_SZ; ++b) acc[b] = zg[b * TWO_H + tid] * w;

    #pragma unroll
    for (int b = 0; b < B_SZ; ++b) {
        float v = acc[b];
        v += __shfl_xor(v, 1);  v += __shfl_xor(v, 2);  v += __shfl_xor(v, 4);
        v += __shfl_xor(v, 8);  v += __shfl_xor(v, 16); v += __shfl_xor(v, 32);
        acc[b] = v;
    }
    __shared__ float red[4][B_SZ];
    const int wave = tid >> 6, lane = tid & 63;
    if (lane == 0) {
        #pragma unroll
        for (int b = 0; b < B_SZ; ++b) red[wave][b] = acc[b];
    }
    __syncthreads();
    if (tid < B_SZ)
        g[tid * H_SZ + j] = red[0][tid] + red[1][tid] + red[2][tid] + red[3][tid] + b2[j];
}

// ---------------------------------------------------------------------------
// 2) Build both neighbor lists. One WAVE per row; ballot-compaction preserves
//    ascending order. grid = (N_SZ, 2) x 64 threads.
// ---------------------------------------------------------------------------
__global__ void csr_kernel(const float* __restrict__ m0, const float* __restrict__ m1,
                           int* __restrict__ i0, int* __restrict__ i1,
                           int* __restrict__ d0, int* __restrict__ d1) {
    const float* mask = blockIdx.y ? m1 : m0;
    int* idx = blockIdx.y ? i1 : i0;
    int* deg = blockIdx.y ? d1 : d0;

    const int row = blockIdx.x;
    const int lane = threadIdx.x;  // 0..63
    const float* mrow = mask + (size_t)row * N_SZ;
    int* irow = idx + (size_t)row * CAP;

    int base = 0;
    #pragma unroll 4
    for (int t = 0; t < N_SZ / 64; ++t) {
        int c = t * 64 + lane;
        bool edge = (mrow[c] == 0.0f);
        unsigned long long ball = __ballot(edge);
        unsigned long long below = ball & ((1ull << lane) - 1ull);
        if (edge) irow[base + __popcll(below)] = c;
        base += __popcll(ball);
    }
    if (lane == 0) deg[row] = base;
}

// ---------------------------------------------------------------------------
// 3) x[b,n,c] = g[b,c] + voxel_emb[n,c]
// ---------------------------------------------------------------------------
__global__ void addemb_kernel(const float* __restrict__ g, const float* __restrict__ emb,
                              float* __restrict__ x) {
    int idx = blockIdx.x * blockDim.x + threadIdx.x;
    int c = idx & 127;
    int n = (idx >> 7) & 1023;
    int b = idx >> 17;
    x[idx] = g[b * H_SZ + c] + emb[n * H_SZ + c];
}

// ---------------------------------------------------------------------------
// 4) Projection, LDS-staged GEMM: out[row,j] = sum_k x[row,k] * WT[k][j].
//    grid = (BN/GR, 2) x 128 threads. Block = GR(16) rows x 128 cols.
//    Thread = (colg = tid&31 -> jq = colg*4, rowg = tid>>5 -> 4 rows).
//    Weights staged ONCE per block in LDS (shared by both waves, kills the
//    per-wave L1 weight streaming that bound rounds 10-13). Inputs staged
//    k-major for broadcast float4 reads. Per k: 2 LDS b128 -> 16 FMA.
// ---------------------------------------------------------------------------
__global__ __launch_bounds__(128) void proj_kernel(
        const float* __restrict__ x, const float* __restrict__ wta,
        const float* __restrict__ wtb,
        float* __restrict__ outa, float* __restrict__ outb) {
    const float* WT = blockIdx.y ? wtb : wta;
    float* out = blockIdx.y ? outb : outa;

    __shared__ float in_t[H_SZ][GR];     // k-major inputs, 8 KB
    __shared__ float wb[H_SZ][H_SZ];     // k-major weights, 64 KB
    const int row0 = blockIdx.x * GR;
    const int tid = threadIdx.x;         // 0..127
    const int colg = tid & 31, jq = colg * 4;
    const int rowg = tid >> 5, rbase = rowg * 4;

    // stage inputs k-major: 16 rows x 32 k4-chunks = 512 float4 slots
    for (int s = tid; s < GR * 32; s += 128) {
        const int r = s & 15, k4 = s >> 4;
        const float4 v = ((const float4*)(x + (size_t)(row0 + r) * H_SZ))[k4];
        in_t[k4 * 4 + 0][r] = v.x; in_t[k4 * 4 + 1][r] = v.y;
        in_t[k4 * 4 + 2][r] = v.z; in_t[k4 * 4 + 3][r] = v.w;
    }
    // stage weights: 128 x 32 float4 slots (coalesced)
    for (int s = tid; s < H_SZ * 32; s += 128) {
        const int k = s >> 5, j4 = s & 31;
        ((float4*)wb[k])[j4] = ((const float4*)(WT + (size_t)k * H_SZ))[j4];
    }
    __syncthreads();

    float acc[4][4];
    #pragma unroll
    for (int i = 0; i < 4; ++i)
        #pragma unroll
        for (int j = 0; j < 4; ++j) acc[i][j] = 0.0f;

    #pragma unroll 4
    for (int k = 0; k < H_SZ; ++k) {
        const float4 a = *(const float4*)&in_t[k][rbase];   // broadcast
        const float4 w = *(const float4*)&wb[k][jq];
        acc[0][0] += a.x * w.x; acc[0][1] += a.x * w.y; acc[0][2] += a.x * w.z; acc[0][3] += a.x * w.w;
        acc[1][0] += a.y * w.x; acc[1][1] += a.y * w.y; acc[1][2] += a.y * w.z; acc[1][3] += a.y * w.w;
        acc[2][0] += a.z * w.x; acc[2][1] += a.z * w.y; acc[2][2] += a.z * w.z; acc[2][3] += a.z * w.w;
        acc[3][0] += a.w * w.x; acc[3][1] += a.w * w.y; acc[3][2] += a.w * w.z; acc[3][3] += a.w * w.w;
    }
    #pragma unroll
    for (int i = 0; i < 4; ++i) {
        float4 v = {acc[i][0], acc[i][1], acc[i][2], acc[i][3]};
        *(float4*)(out + (size_t)(row0 + rbase + i) * H_SZ + jq) = v;
    }
}

// ---------------------------------------------------------------------------
// 5) Sparse masked attention + ELU, coalesced neighbor-parallel.
//    (round-10 proven config, unchanged)
// ---------------------------------------------------------------------------
__global__ __launch_bounds__(256) void attn_kernel(
        const float* __restrict__ Wha, const float* __restrict__ Whb,
        const int* __restrict__ ia, const int* __restrict__ ib,
        const int* __restrict__ da, const int* __restrict__ db,
        float* __restrict__ oa, float* __restrict__ ob) {
    const float* Wh = blockIdx.y ? Whb : Wha;
    const int* idx = blockIdx.y ? ib : ia;
    const int* deg = blockIdx.y ? db : da;
    float* out = blockIdx.y ? ob : oa;

    const int bid = blockIdx.x;
    const int b = bid & 7;                                  // batch -> XCD
    const int i = ((bid >> 3) << 2) | (threadIdx.x >> 6);   // row
    const int bi = b * N_SZ + i;
    const int lane = threadIdx.x & 63;
    const int c = lane & 31;      // 16B chunk id within a 512B row
    const int e2 = lane >> 5;     // which of the 2 edges per instruction

    // q chunk (4 floats of head c>>3), pre-scaled: 1/sqrt(32) * log2(e)
    float4 q4 = *(const float4*)(Wh + (size_t)bi * H_SZ + c * 4);
    q4.x *= 0.25505654741110714f; q4.y *= 0.25505654741110714f;
    q4.z *= 0.25505654741110714f; q4.w *= 0.25505654741110714f;

    const int dg = deg[i];
    const int* row = idx + (size_t)i * CAP;
    int idxv0 = row[lane] & 1023;
    int idxv1 = (dg > 64) ? (row[64 + lane] & 1023) : 0;

    const float* kbase = Wh + (size_t)b * NH_STRIDE;

    float4 acc = {0.0f, 0.0f, 0.0f, 0.0f};
    float l = 0.0f;

    const int nseg = (dg + 15) >> 4;
    for (int seg = 0; seg < nseg; ++seg) {
        const int srcv = (seg >= 4) ? idxv1 : idxv0;
        const int off16 = (seg & 3) << 4;
        float4 kv[8];
        #pragma unroll
        for (int t = 0; t < 8; ++t) {
            const int ja = __builtin_amdgcn_readlane(srcv, off16 + 2 * t);
            const int jb = __builtin_amdgcn_readlane(srcv, off16 + 2 * t + 1);
            const int j = e2 ? jb : ja;
            kv[t] = *(const float4*)(kbase + (size_t)j * H_SZ + c * 4);
        }
        const int ebase = seg << 4;
        #pragma unroll
        for (int t = 0; t < 8; ++t) {
            float s = q4.x * kv[t].x + q4.y * kv[t].y + q4.z * kv[t].z + q4.w * kv[t].w;
            s += __shfl_xor(s, 1);
            s += __shfl_xor(s, 2);
            s += __shfl_xor(s, 4);
            const bool valid = (ebase + 2 * t + e2) < dg;
            const float p = valid ? __builtin_amdgcn_exp2f(s) : 0.0f;
            l += p;
            acc.x += p * kv[t].x; acc.y += p * kv[t].y;
            acc.z += p * kv[t].z; acc.w += p * kv[t].w;
        }
    }

    l += __shfl_xor(l, 32);
    acc.x += __shfl_xor(acc.x, 32);
    acc.y += __shfl_xor(acc.y, 32);
    acc.z += __shfl_xor(acc.z, 32);
    acc.w += __shfl_xor(acc.w, 32);

    if (e2 == 0) {
        const float inv = 1.0f / l;
        float4 v;
        float hp;
        hp = acc.x * inv;
        v.x = (hp > 0.0f) ? hp : (__builtin_amdgcn_exp2f(hp * 1.4426950408889634f) - 1.0f);
        hp = acc.y * inv;
        v.y = (hp > 0.0f) ? hp : (__builtin_amdgcn_exp2f(hp * 1.4426950408889634f) - 1.0f);
        hp = acc.z * inv;
        v.z = (hp > 0.0f) ? hp : (__builtin_amdgcn_exp2f(hp * 1.4426950408889634f) - 1.0f);
        hp = acc.w * inv;
        v.w = (hp > 0.0f) ? hp : (__builtin_amdgcn_exp2f(hp * 1.4426950408889634f) - 1.0f);
        *(float4*)(out + (size_t)bi * H_SZ + c * 4) = v;
    }
}

// ---------------------------------------------------------------------------
// 6) Fusion, LDS-staged GEMM over 3 k-segments (hf, hr, x) sharing one weight
//    buffer (+ optional fused readout). grid = BN/GR = 512 blocks x 128 thr.
//    Same thread tile as proj: 4 rows x 4 cols; weights staged once per block
//    per segment. Summation order k-ascending, segments hf->hr->x: identical
//    to previous rounds (bit-exact).
// ---------------------------------------------------------------------------
__global__ __launch_bounds__(128) void fusion_kernel(
        const float* __restrict__ hf, const float* __restrict__ hr,
        const float* __restrict__ x,
        const float* __restrict__ wtfu, const float* __restrict__ bfu,
        const float* __restrict__ wtsk, const float* __restrict__ bsk,
        float* __restrict__ out,
        const float* __restrict__ Wro, const float* __restrict__ bro,
        float* __restrict__ pred) {
    __shared__ float in_t[H_SZ][GR];     // k-major inputs, 8 KB
    __shared__ float wb[H_SZ][H_SZ];     // k-major weights, 64 KB
    __shared__ float red[GR];
    const int row0 = blockIdx.x * GR;
    const int tid = threadIdx.x;         // 0..127
    const int colg = tid & 31, jq = colg * 4;
    const int rowg = tid >> 5, rbase = rowg * 4;

    float acc[4][4];
    #pragma unroll
    for (int i = 0; i < 4; ++i)
        #pragma unroll
        for (int j = 0; j < 4; ++j) acc[i][j] = 0.0f;

    for (int seg = 0; seg < 3; ++seg) {
        const float* src = (seg == 0) ? hf : ((seg == 1) ? hr : x);
        const float* wseg = (seg < 2) ? (wtfu + (size_t)seg * H_SZ * H_SZ) : wtsk;

        __syncthreads();   // previous segment's reads done before overwrite
        for (int s = tid; s < GR * 32; s += 128) {
            const int r = s & 15, k4 = s >> 4;
            const float4 v = ((const float4*)(src + (size_t)(row0 + r) * H_SZ))[k4];
            in_t[k4 * 4 + 0][r] = v.x; in_t[k4 * 4 + 1][r] = v.y;
            in_t[k4 * 4 + 2][r] = v.z; in_t[k4 * 4 + 3][r] = v.w;
        }
        for (int s = tid; s < H_SZ * 32; s += 128) {
            const int k = s >> 5, j4 = s & 31;
            ((float4*)wb[k])[j4] = ((const float4*)(wseg + (size_t)k * H_SZ))[j4];
        }
        __syncthreads();

        #pragma unroll 4
        for (int k = 0; k < H_SZ; ++k) {
            const float4 a = *(const float4*)&in_t[k][rbase];   // broadcast
            const float4 w = *(const float4*)&wb[k][jq];
            acc[0][0] += a.x * w.x; acc[0][1] += a.x * w.y; acc[0][2] += a.x * w.z; acc[0][3] += a.x * w.w;
            acc[1][0] += a.y * w.x; acc[1][1] += a.y * w.y; acc[1][2] += a.y * w.z; acc[1][3] += a.y * w.w;
            acc[2][0] += a.z * w.x; acc[2][1] += a.z * w.y; acc[2][2] += a.z * w.z; acc[2][3] += a.z * w.w;
            acc[3][0] += a.w * w.x; acc[3][1] += a.w * w.y; acc[3][2] += a.w * w.z; acc[3][3] += a.w * w.w;
        }
    }

    const float4 bf = *(const float4*)(bfu + jq);
    const float4 bs = *(const float4*)(bsk + jq);
    const float bias[4] = {bf.x + bs.x, bf.y + bs.y, bf.z + bs.z, bf.w + bs.w};

    if (pred == nullptr) {
        #pragma unroll
        for (int i = 0; i < 4; ++i) {
            float4 v = {acc[i][0] + bias[0], acc[i][1] + bias[1],
                        acc[i][2] + bias[2], acc[i][3] + bias[3]};
            *(float4*)(out + (size_t)(row0 + rbase + i) * H_SZ + jq) = v;
        }
    } else {
        const float4 wr = *(const float4*)(Wro + jq);
        #pragma unroll
        for (int i = 0; i < 4; ++i) {
            float t = (acc[i][0] + bias[0]) * wr.x + (acc[i][1] + bias[1]) * wr.y
                    + (acc[i][2] + bias[2]) * wr.z + (acc[i][3] + bias[3]) * wr.w;
            t += __shfl_xor(t, 1);  t += __shfl_xor(t, 2);  t += __shfl_xor(t, 4);
            t += __shfl_xor(t, 8);  t += __shfl_xor(t, 16);
            if (colg == 0) red[rbase + i] = t;
        }
        __syncthreads();
        if (tid < GR) pred[row0 + tid] = red[tid] + bro[0];
    }
}

// ---------------------------------------------------------------------------
extern "C" void kernel_launch(void* const* d_in, const int* in_sizes, int n_in,
                              void* d_out, int out_size, void* d_ws, size_t ws_size,
                              hipStream_t stream) {
    const float* stim   = (const float*)d_in[0];
    const float* W_enc1 = (const float*)d_in[1];
    const float* b_enc1 = (const float*)d_in[2];
    const float* ln_g   = (const float*)d_in[3];
    const float* ln_b   = (const float*)d_in[4];
    const float* W_enc2 = (const float*)d_in[5];
    const float* b_enc2 = (const float*)d_in[6];
    const float* vox    = (const float*)d_in[7];
    const float* W_f1   = (const float*)d_in[8];
    const float* W_r1   = (const float*)d_in[9];
    const float* W_f2   = (const float*)d_in[10];
    const float* W_r2   = (const float*)d_in[11];
    const float* W_fu1  = (const float*)d_in[12];
    const float* b_fu1  = (const float*)d_in[13];
    const float* W_fu2  = (const float*)d_in[14];
    const float* b_fu2  = (const float*)d_in[15];
    const float* W_sk1  = (const float*)d_in[16];
    const float* b_sk1  = (const float*)d_in[17];
    const float* W_sk2  = (const float*)d_in[18];
    const float* b_sk2  = (const float*)d_in[19];
    const float* W_ro   = (const float*)d_in[20];
    const float* b_ro   = (const float*)d_in[21];
    const float* mask_f = (const float*)d_in[22];
    const float* mask_r = (const float*)d_in[23];

    float* pred = (float*)d_out;

    // workspace layout (floats)
    float* ws  = (float*)d_ws;
    float* z   = ws;                    // 8*256
    float* zg  = z + 2048;              // 8*256
    float* g   = zg + 2048;             // 8*128
    float* x   = g + 1024;              // 8*1024*128
    float* Whf = x + 1048576;
    float* Whr = Whf + 1048576;
    float* hf  = Whr + 1048576;
    float* hr  = hf + 1048576;
    int* idxf  = (int*)(hr + 1048576);  // 1024*CAP
    int* idxr  = idxf + (size_t)N_SZ * CAP;
    int* degf  = idxr + (size_t)N_SZ * CAP;
    int* degr  = degf + N_SZ;
    float* wt  = (float*)(degr + N_SZ); // 163840 floats: transposed weights
    float* wtfu1 = wt;
    float* wtfu2 = wt + 32768;
    float* wtsk1 = wt + 65536;
    float* wtsk2 = wt + 81920;
    float* wtf1  = wt + 98304;
    float* wtr1  = wt + 114688;
    float* wtf2  = wt + 131072;
    float* wtr2  = wt + 147456;

    const int BN = B_SZ * N_SZ;  // 8192

    // weight transposes (independent of everything else)
    transw_kernel<<<dim3(256, 8), 128, 0, stream>>>(W_fu1, W_fu2, W_sk1, W_sk2,
                                                    W_f1, W_r1, W_f2, W_r2, wt);
    // encoder
    enc1_kernel<<<TWO_H, 256, 0, stream>>>(stim, W_enc1, b_enc1, z);
    enc2_kernel<<<B_SZ, 256, 0, stream>>>(z, ln_g, ln_b, zg);
    enc3_kernel<<<H_SZ, 256, 0, stream>>>(zg, W_enc2, b_enc2, g);
    // neighbor lists (both masks in one launch)
    csr_kernel<<<dim3(N_SZ, 2), 64, 0, stream>>>(mask_f, mask_r, idxf, idxr, degf, degr);
    // x = g + voxel_emb
    addemb_kernel<<<(BN * H_SZ) / 256, 256, 0, stream>>>(g, vox, x);

    // ---- GAT layer 1 ----
    proj_kernel<<<dim3(BN / GR, 2), 128, 0, stream>>>(x, wtf1, wtr1, Whf, Whr);
    attn_kernel<<<dim3(BN / 4, 2), 256, 0, stream>>>(Whf, Whr, idxf, idxr, degf, degr, hf, hr);
    fusion_kernel<<<BN / GR, 128, 0, stream>>>(hf, hr, x, wtfu1, b_fu1, wtsk1, b_sk1, x,
                                               nullptr, nullptr, nullptr);

    // ---- GAT layer 2 ----
    proj_kernel<<<dim3(BN / GR, 2), 128, 0, stream>>>(x, wtf2, wtr2, Whf, Whr);
    attn_kernel<<<dim3(BN / 4, 2), 256, 0, stream>>>(Whf, Whr, idxf, idxr, degf, degr, hf, hr);
    fusion_kernel<<<BN / GR, 128, 0, stream>>>(hf, hr, x, wtfu2, b_fu2, wtsk2, b_sk2, nullptr,
                                               W_ro, b_ro, pred);
}

// Round 15
// 109.269 us; speedup vs baseline: 2.0998x; 2.0343x over previous
//
#include <hip/hip_runtime.h>
#include <hip/hip_bf16.h>
#include <math.h>

// Problem constants
#define B_SZ 8
#define N_SZ 1024
#define D_IN 3072
#define H_SZ 128
#define NH 4
#define DH 32
#define TWO_H 256
#define LN_EPS 1e-5f
#define CAP 128    // max neighbors per row (binomial max deg ~80 << 128)
#define NH_STRIDE (N_SZ * H_SZ)

typedef __attribute__((ext_vector_type(8))) short bf16x8;
typedef __attribute__((ext_vector_type(8))) unsigned short u16x8;
typedef __attribute__((ext_vector_type(4))) float f32x4;

// round-to-nearest-even fp32 -> bf16 bits
__device__ inline unsigned short f2bf(float f) {
    unsigned int u = __builtin_bit_cast(unsigned int, f);
    u += 0x7fffu + ((u >> 16) & 1u);
    return (unsigned short)(u >> 16);
}

// ---------------------------------------------------------------------------
// 0) Convert all GEMM weights to bf16 ONCE (W-row-major [j][k] kept: that IS
//    the MFMA B-fragment-friendly layout, B[k][col] = W[col][k] contiguous).
//    wb16 layout (ushorts): [0] wcat1[128][384] = [Wfu1[j][0:256] | Wsk1[j]]
//    [49152] wcat2 ; [98304] Wf1 ; [114688] Wr1 ; [131072] Wf2 ; [147456] Wr2
// ---------------------------------------------------------------------------
__global__ void cvtw_kernel(const float* __restrict__ Wfu1, const float* __restrict__ Wsk1,
                            const float* __restrict__ Wfu2, const float* __restrict__ Wsk2,
                            const float* __restrict__ Wf1, const float* __restrict__ Wr1,
                            const float* __restrict__ Wf2, const float* __restrict__ Wr2,
                            unsigned short* __restrict__ wb) {
    const int j = blockIdx.x;   // 0..127
    const int t = threadIdx.x;  // 0..255
    wb[j * 384 + t] = f2bf(Wfu1[j * 256 + t]);
    wb[49152 + j * 384 + t] = f2bf(Wfu2[j * 256 + t]);
    if (t < 128) {
        wb[j * 384 + 256 + t]         = f2bf(Wsk1[j * 128 + t]);
        wb[49152 + j * 384 + 256 + t] = f2bf(Wsk2[j * 128 + t]);
        wb[98304  + j * 128 + t] = f2bf(Wf1[j * 128 + t]);
        wb[114688 + j * 128 + t] = f2bf(Wr1[j * 128 + t]);
        wb[131072 + j * 128 + t] = f2bf(Wf2[j * 128 + t]);
        wb[147456 + j * 128 + t] = f2bf(Wr2[j * 128 + t]);
    }
}

// ---------------------------------------------------------------------------
// 1a) enc1: z[b][j] = b1[j] + dot(stim[b,:], W1[j,:])
// ---------------------------------------------------------------------------
__global__ void enc1_kernel(const float* __restrict__ stim,
                            const float* __restrict__ W1, const float* __restrict__ b1,
                            float* __restrict__ z) {
    const int j = blockIdx.x;     // 0..255
    const int tid = threadIdx.x;  // 0..255
    const float4* w4 = (const float4*)(W1 + (size_t)j * D_IN);
    const float4* s4 = (const float4*)stim;

    float acc[B_SZ];
    #pragma unroll
    for (int b = 0; b < B_SZ; ++b) acc[b] = 0.0f;

    #pragma unroll
    for (int i = 0; i < D_IN / 4 / 256; ++i) {  // 3 iters
        const int k4 = tid + i * 256;
        const float4 w = w4[k4];
        #pragma unroll
        for (int b = 0; b < B_SZ; ++b) {
            const float4 s = s4[b * (D_IN / 4) + k4];
            acc[b] += s.x * w.x + s.y * w.y + s.z * w.z + s.w * w.w;
        }
    }

    #pragma unroll
    for (int b = 0; b < B_SZ; ++b) {
        float v = acc[b];
        v += __shfl_xor(v, 1);  v += __shfl_xor(v, 2);  v += __shfl_xor(v, 4);
        v += __shfl_xor(v, 8);  v += __shfl_xor(v, 16); v += __shfl_xor(v, 32);
        acc[b] = v;
    }
    __shared__ float red[4][B_SZ];
    const int wave = tid >> 6, lane = tid & 63;
    if (lane == 0) {
        #pragma unroll
        for (int b = 0; b < B_SZ; ++b) red[wave][b] = acc[b];
    }
    __syncthreads();
    if (tid < B_SZ) {
        float v = red[0][tid] + red[1][tid] + red[2][tid] + red[3][tid];
        z[tid * TWO_H + j] = v + b1[j];
    }
}

// ---------------------------------------------------------------------------
// 1b) enc2: LayerNorm + exact GELU over z rows. grid = 8 blocks x 256 threads.
// ---------------------------------------------------------------------------
__global__ void enc2_kernel(const float* __restrict__ z,
                            const float* __restrict__ lng, const float* __restrict__ lnb,
                            float* __restrict__ zg) {
    __shared__ float red[TWO_H];
    const int b = blockIdx.x;
    const int tid = threadIdx.x;

    float zi = z[b * TWO_H + tid];
    red[tid] = zi; __syncthreads();
    for (int s = 128; s > 0; s >>= 1) { if (tid < s) red[tid] += red[tid + s]; __syncthreads(); }
    float mu = red[0] * (1.0f / TWO_H);
    __syncthreads();
    float dz = zi - mu;
    red[tid] = dz * dz; __syncthreads();
    for (int s = 128; s > 0; s >>= 1) { if (tid < s) red[tid] += red[tid + s]; __syncthreads(); }
    float var = red[0] * (1.0f / TWO_H);

    float zn = dz * (1.0f / sqrtf(var + LN_EPS)) * lng[tid] + lnb[tid];
    zg[b * TWO_H + tid] = 0.5f * zn * (1.0f + erff(zn * 0.70710678118654752f));
}

// ---------------------------------------------------------------------------
// 1c) enc3: g[b][j] = b2[j] + dot(zg[b,:], W2[j,:])
// ---------------------------------------------------------------------------
__global__ void enc3_kernel(const float* __restrict__ zg,
                            const float* __restrict__ W2, const float* __restrict__ b2,
                            float* __restrict__ g) {
    const int j = blockIdx.x;     // 0..127
    const int tid = threadIdx.x;  // 0..255
    const float w = W2[(size_t)j * TWO_H + tid];

    float acc[B_SZ];
    #pragma unroll
    for (int b = 0; b < B_SZ; ++b) acc[b] = zg[b * TWO_H + tid] * w;

    #pragma unroll
    for (int b = 0; b < B_SZ; ++b) {
        float v = acc[b];
        v += __shfl_xor(v, 1);  v += __shfl_xor(v, 2);  v += __shfl_xor(v, 4);
        v += __shfl_xor(v, 8);  v += __shfl_xor(v, 16); v += __shfl_xor(v, 32);
        acc[b] = v;
    }
    __shared__ float red[4][B_SZ];
    const int wave = tid >> 6, lane = tid & 63;
    if (lane == 0) {
        #pragma unroll
        for (int b = 0; b < B_SZ; ++b) red[wave][b] = acc[b];
    }
    __syncthreads();
    if (tid < B_SZ)
        g[tid * H_SZ + j] = red[0][tid] + red[1][tid] + red[2][tid] + red[3][tid] + b2[j];
}

// ---------------------------------------------------------------------------
// 2) Build both neighbor lists. One WAVE per row; ballot-compaction preserves
//    ascending order. grid = (N_SZ, 2) x 64 threads. deg capped at CAP=128.
// ---------------------------------------------------------------------------
__global__ void csr_kernel(const float* __restrict__ m0, const float* __restrict__ m1,
                           int* __restrict__ i0, int* __restrict__ i1,
                           int* __restrict__ d0, int* __restrict__ d1) {
    const float* mask = blockIdx.y ? m1 : m0;
    int* idx = blockIdx.y ? i1 : i0;
    int* deg = blockIdx.y ? d1 : d0;

    const int row = blockIdx.x;
    const int lane = threadIdx.x;  // 0..63
    const float* mrow = mask + (size_t)row * N_SZ;
    int* irow = idx + (size_t)row * CAP;

    int base = 0;
    #pragma unroll 4
    for (int t = 0; t < N_SZ / 64; ++t) {
        int c = t * 64 + lane;
        bool edge = (mrow[c] == 0.0f);
        unsigned long long ball = __ballot(edge);
        unsigned long long below = ball & ((1ull << lane) - 1ull);
        if (edge) {
            int p = base + __popcll(below);
            if (p < CAP) irow[p] = c;
        }
        base += __popcll(ball);
    }
    if (lane == 0) deg[row] = (base < CAP) ? base : CAP;
}

// ---------------------------------------------------------------------------
// 3) x[b,n,c] = g[b,c] + voxel_emb[n,c]
// ---------------------------------------------------------------------------
__global__ void addemb_kernel(const float* __restrict__ g, const float* __restrict__ emb,
                              float* __restrict__ x) {
    int idx = blockIdx.x * blockDim.x + threadIdx.x;
    int c = idx & 127;
    int n = (idx >> 7) & 1023;
    int b = idx >> 17;
    x[idx] = g[b * H_SZ + c] + emb[n * H_SZ + c];
}

// ---------------------------------------------------------------------------
// 4) MFMA GEMM: out[row][j] = sum_seg sum_k a_seg[row][k] * W[j][seg*128+k]
//    (+ optional biases). bf16 inputs (RNE-converted), fp32 accumulation via
//    v_mfma_f32_16x16x32_bf16.
//    Block = 32 rows x 64 cols, 256 thr = 4 waves (2M x 2N); wave = 16r x 32c
//    = 1 A-frag x 2 B-frags per K-step. K staged in 128-chunks:
//    As[32][128] + Bs[64][128] bf16 = 24 KB LDS, XOR-swizzled 16B granules
//    (granule ^= row&7) to avoid the D=128 same-bank pathology (G4).
//    Fragment layouts (16x16x32): A lane l: row=l%16, k=(l/16)*8+j ;
//    B lane l: col=l%16, k=(l/16)*8+j ; D lane l reg r: row=(l/16)*4+r,
//    col=l%16 [guide §3, m89-verified].
// ---------------------------------------------------------------------------
template<int NSEG>
__global__ __launch_bounds__(256) void gemm_mfma(
        const float* __restrict__ a0, const float* __restrict__ a1,
        const float* __restrict__ a2,
        const unsigned short* __restrict__ wba, const unsigned short* __restrict__ wbb,
        const float* __restrict__ bias1, const float* __restrict__ bias2,
        float* __restrict__ outa, float* __restrict__ outb) {
    const unsigned short* wb = blockIdx.y ? wbb : wba;
    float* out = blockIdx.y ? outb : outa;
    const int KW = NSEG * 128;   // weight row stride (ushorts)

    __shared__ __align__(16) short As[32 * 128];
    __shared__ __align__(16) short Bs[64 * 128];

    const int bid = blockIdx.x;
    const int ct = bid & 1, rt = bid >> 1;
    const int row0 = rt * 32, col0 = ct * 64;
    const int tid = threadIdx.x;
    const int lane = tid & 63, w = tid >> 6;
    const int wm = w >> 1, wn = w & 1;
    const int lrow = lane & 15, lk = lane >> 4;

    f32x4 acc0 = {0.f, 0.f, 0.f, 0.f};
    f32x4 acc1 = {0.f, 0.f, 0.f, 0.f};

    for (int seg = 0; seg < NSEG; ++seg) {
        const float* src = (seg == 0) ? a0 : ((seg == 1) ? a1 : a2);
        if (seg) __syncthreads();
        // stage A: 32 rows x 128 k, fp32 -> bf16, swizzled 16B granules
        for (int gi = tid; gi < 512; gi += 256) {
            const int r = gi >> 4, kq = gi & 15;
            const float4* sp = (const float4*)(src + (size_t)(row0 + r) * H_SZ) + kq * 2;
            const float4 v0 = sp[0], v1 = sp[1];
            u16x8 t;
            t[0] = f2bf(v0.x); t[1] = f2bf(v0.y); t[2] = f2bf(v0.z); t[3] = f2bf(v0.w);
            t[4] = f2bf(v1.x); t[5] = f2bf(v1.y); t[6] = f2bf(v1.z); t[7] = f2bf(v1.w);
            *(u16x8*)&As[r * 128 + ((kq * 8) ^ ((r & 7) << 3))] = t;
        }
        // stage B: 64 cols x 128 k (already bf16, contiguous 16B per granule)
        for (int gi = tid; gi < 1024; gi += 256) {
            const int c = gi >> 4, kq = gi & 15;
            const float4 v = *(const float4*)(wb + (size_t)(col0 + c) * KW + seg * 128 + kq * 8);
            *(float4*)&Bs[c * 128 + ((kq * 8) ^ ((c & 7) << 3))] = v;
        }
        __syncthreads();

        #pragma unroll
        for (int ks = 0; ks < 4; ++ks) {
            const int kof = ks * 32 + lk * 8;
            const int r = wm * 16 + lrow;
            const bf16x8 a = *(const bf16x8*)&As[r * 128 + (kof ^ ((r & 7) << 3))];
            const int c0 = wn * 32 + lrow;
            const bf16x8 b0 = *(const bf16x8*)&Bs[c0 * 128 + (kof ^ ((c0 & 7) << 3))];
            const int c1 = c0 + 16;
            const bf16x8 b1 = *(const bf16x8*)&Bs[c1 * 128 + (kof ^ ((c1 & 7) << 3))];
            acc0 = __builtin_amdgcn_mfma_f32_16x16x32_bf16(a, b0, acc0, 0, 0, 0);
            acc1 = __builtin_amdgcn_mfma_f32_16x16x32_bf16(a, b1, acc1, 0, 0, 0);
        }
    }

    // epilogue: D lane l reg r -> row=(l>>4)*4+r, col=l&15
    const int rb = row0 + wm * 16 + lk * 4;
    #pragma unroll
    for (int fc = 0; fc < 2; ++fc) {
        const int c = col0 + wn * 32 + fc * 16 + lrow;
        const float bias = (bias1 ? bias1[c] : 0.0f) + (bias2 ? bias2[c] : 0.0f);
        const f32x4 a = fc ? acc1 : acc0;
        #pragma unroll
        for (int rr = 0; rr < 4; ++rr)
            out[(size_t)(rb + rr) * H_SZ + c] = a[rr] + bias;
    }
}

// ---------------------------------------------------------------------------
// 5) Sparse masked attention + ELU, coalesced neighbor-parallel.
//    (round-10 proven config; idx stride = CAP = 128)
// ---------------------------------------------------------------------------
__global__ __launch_bounds__(256) void attn_kernel(
        const float* __restrict__ Wha, const float* __restrict__ Whb,
        const int* __restrict__ ia, const int* __restrict__ ib,
        const int* __restrict__ da, const int* __restrict__ db,
        float* __restrict__ oa, float* __restrict__ ob) {
    const float* Wh = blockIdx.y ? Whb : Wha;
    const int* idx = blockIdx.y ? ib : ia;
    const int* deg = blockIdx.y ? db : da;
    float* out = blockIdx.y ? ob : oa;

    const int bid = blockIdx.x;
    const int b = bid & 7;                                  // batch -> XCD
    const int i = ((bid >> 3) << 2) | (threadIdx.x >> 6);   // row
    const int bi = b * N_SZ + i;
    const int lane = threadIdx.x & 63;
    const int c = lane & 31;      // 16B chunk id within a 512B row
    const int e2 = lane >> 5;     // which of the 2 edges per instruction

    // q chunk (4 floats of head c>>3), pre-scaled: 1/sqrt(32) * log2(e)
    float4 q4 = *(const float4*)(Wh + (size_t)bi * H_SZ + c * 4);
    q4.x *= 0.25505654741110714f; q4.y *= 0.25505654741110714f;
    q4.z *= 0.25505654741110714f; q4.w *= 0.25505654741110714f;

    const int dg = deg[i];
    const int* row = idx + (size_t)i * CAP;
    int idxv0 = row[lane] & 1023;
    int idxv1 = (dg > 64) ? (row[64 + lane] & 1023) : 0;

    const float* kbase = Wh + (size_t)b * NH_STRIDE;

    float4 acc = {0.0f, 0.0f, 0.0f, 0.0f};
    float l = 0.0f;

    const int nseg = (dg + 15) >> 4;
    for (int seg = 0; seg < nseg; ++seg) {
        const int srcv = (seg >= 4) ? idxv1 : idxv0;
        const int off16 = (seg & 3) << 4;
        float4 kv[8];
        #pragma unroll
        for (int t = 0; t < 8; ++t) {
            const int ja = __builtin_amdgcn_readlane(srcv, off16 + 2 * t);
            const int jb = __builtin_amdgcn_readlane(srcv, off16 + 2 * t + 1);
            const int j = e2 ? jb : ja;
            kv[t] = *(const float4*)(kbase + (size_t)j * H_SZ + c * 4);
        }
        const int ebase = seg << 4;
        #pragma unroll
        for (int t = 0; t < 8; ++t) {
            float s = q4.x * kv[t].x + q4.y * kv[t].y + q4.z * kv[t].z + q4.w * kv[t].w;
            s += __shfl_xor(s, 1);
            s += __shfl_xor(s, 2);
            s += __shfl_xor(s, 4);
            const bool valid = (ebase + 2 * t + e2) < dg;
            const float p = valid ? __builtin_amdgcn_exp2f(s) : 0.0f;
            l += p;
            acc.x += p * kv[t].x; acc.y += p * kv[t].y;
            acc.z += p * kv[t].z; acc.w += p * kv[t].w;
        }
    }

    l += __shfl_xor(l, 32);
    acc.x += __shfl_xor(acc.x, 32);
    acc.y += __shfl_xor(acc.y, 32);
    acc.z += __shfl_xor(acc.z, 32);
    acc.w += __shfl_xor(acc.w, 32);

    if (e2 == 0) {
        const float inv = 1.0f / l;
        float4 v;
        float hp;
        hp = acc.x * inv;
        v.x = (hp > 0.0f) ? hp : (__builtin_amdgcn_exp2f(hp * 1.4426950408889634f) - 1.0f);
        hp = acc.y * inv;
        v.y = (hp > 0.0f) ? hp : (__builtin_amdgcn_exp2f(hp * 1.4426950408889634f) - 1.0f);
        hp = acc.z * inv;
        v.z = (hp > 0.0f) ? hp : (__builtin_amdgcn_exp2f(hp * 1.4426950408889634f) - 1.0f);
        hp = acc.w * inv;
        v.w = (hp > 0.0f) ? hp : (__builtin_amdgcn_exp2f(hp * 1.4426950408889634f) - 1.0f);
        *(float4*)(out + (size_t)bi * H_SZ + c * 4) = v;
    }
}

// ---------------------------------------------------------------------------
// 6) Readout: pred[row] = dot(x[row,:], W_ro) + b_ro. 64 threads/block.
// ---------------------------------------------------------------------------
__global__ void readout_kernel(const float* __restrict__ x, const float* __restrict__ Wro,
                               const float* __restrict__ bro, float* __restrict__ out) {
    const int row = blockIdx.x;
    const int lane = threadIdx.x;  // 0..63
    float s = x[(size_t)row * H_SZ + lane] * Wro[lane]
            + x[(size_t)row * H_SZ + 64 + lane] * Wro[64 + lane];
    #pragma unroll
    for (int m = 32; m >= 1; m >>= 1) s += __shfl_xor(s, m);
    if (lane == 0) out[row] = s + bro[0];
}

// ---------------------------------------------------------------------------
extern "C" void kernel_launch(void* const* d_in, const int* in_sizes, int n_in,
                              void* d_out, int out_size, void* d_ws, size_t ws_size,
                              hipStream_t stream) {
    const float* stim   = (const float*)d_in[0];
    const float* W_enc1 = (const float*)d_in[1];
    const float* b_enc1 = (const float*)d_in[2];
    const float* ln_g   = (const float*)d_in[3];
    const float* ln_b   = (const float*)d_in[4];
    const float* W_enc2 = (const float*)d_in[5];
    const float* b_enc2 = (const float*)d_in[6];
    const float* vox    = (const float*)d_in[7];
    const float* W_f1   = (const float*)d_in[8];
    const float* W_r1   = (const float*)d_in[9];
    const float* W_f2   = (const float*)d_in[10];
    const float* W_r2   = (const float*)d_in[11];
    const float* W_fu1  = (const float*)d_in[12];
    const float* b_fu1  = (const float*)d_in[13];
    const float* W_fu2  = (const float*)d_in[14];
    const float* b_fu2  = (const float*)d_in[15];
    const float* W_sk1  = (const float*)d_in[16];
    const float* b_sk1  = (const float*)d_in[17];
    const float* W_sk2  = (const float*)d_in[18];
    const float* b_sk2  = (const float*)d_in[19];
    const float* W_ro   = (const float*)d_in[20];
    const float* b_ro   = (const float*)d_in[21];
    const float* mask_f = (const float*)d_in[22];
    const float* mask_r = (const float*)d_in[23];

    float* pred = (float*)d_out;

    // workspace layout (floats)
    float* ws  = (float*)d_ws;
    float* z   = ws;                    // 8*256
    float* zg  = z + 2048;              // 8*256
    float* g   = zg + 2048;             // 8*128
    float* x   = g + 1024;              // 8*1024*128
    float* Whf = x + 1048576;
    float* Whr = Whf + 1048576;
    float* hf  = Whr + 1048576;
    float* hr  = hf + 1048576;
    float* x2  = hr + 1048576;
    int* idxf  = (int*)(x2 + 1048576);  // 1024*CAP
    int* idxr  = idxf + N_SZ * CAP;
    int* degf  = idxr + N_SZ * CAP;
    int* degr  = degf + N_SZ;
    unsigned short* wb16 = (unsigned short*)(degr + N_SZ);   // 163840 ushorts
    unsigned short* wcat1 = wb16;
    unsigned short* wcat2 = wb16 + 49152;
    unsigned short* wpf1  = wb16 + 98304;
    unsigned short* wpr1  = wb16 + 114688;
    unsigned short* wpf2  = wb16 + 131072;
    unsigned short* wpr2  = wb16 + 147456;

    const int BN = B_SZ * N_SZ;  // 8192

    // weight bf16 conversion (independent of everything else)
    cvtw_kernel<<<H_SZ, 256, 0, stream>>>(W_fu1, W_sk1, W_fu2, W_sk2,
                                          W_f1, W_r1, W_f2, W_r2, wb16);
    // encoder
    enc1_kernel<<<TWO_H, 256, 0, stream>>>(stim, W_enc1, b_enc1, z);
    enc2_kernel<<<B_SZ, 256, 0, stream>>>(z, ln_g, ln_b, zg);
    enc3_kernel<<<H_SZ, 256, 0, stream>>>(zg, W_enc2, b_enc2, g);
    // neighbor lists (both masks in one launch)
    csr_kernel<<<dim3(N_SZ, 2), 64, 0, stream>>>(mask_f, mask_r, idxf, idxr, degf, degr);
    // x = g + voxel_emb
    addemb_kernel<<<(BN * H_SZ) / 256, 256, 0, stream>>>(g, vox, x);

    // ---- GAT layer 1 ----
    gemm_mfma<1><<<dim3(BN / 32 * 2, 2), 256, 0, stream>>>(
        x, x, x, wpf1, wpr1, nullptr, nullptr, Whf, Whr);
    attn_kernel<<<dim3(BN / 4, 2), 256, 0, stream>>>(Whf, Whr, idxf, idxr, degf, degr, hf, hr);
    gemm_mfma<3><<<dim3(BN / 32 * 2, 1), 256, 0, stream>>>(
        hf, hr, x, wcat1, wcat1, b_fu1, b_sk1, x2, x2);

    // ---- GAT layer 2 ----
    gemm_mfma<1><<<dim3(BN / 32 * 2, 2), 256, 0, stream>>>(
        x2, x2, x2, wpf2, wpr2, nullptr, nullptr, Whf, Whr);
    attn_kernel<<<dim3(BN / 4, 2), 256, 0, stream>>>(Whf, Whr, idxf, idxr, degf, degr, hf, hr);
    gemm_mfma<3><<<dim3(BN / 32 * 2, 1), 256, 0, stream>>>(
        hf, hr, x2, wcat2, wcat2, b_fu2, b_sk2, x, x);

    // readout
    readout_kernel<<<BN, 64, 0, stream>>>(x, W_ro, b_ro, pred);
}